// Round 3
// baseline (590.258 us; speedup 1.0000x reference)
//
#include <hip/hip_runtime.h>
#include <hip/hip_bf16.h>

#define NROW 131072   // B*L
#define D 256
#define K 320
#define BN_EPS 1e-5f

#define RT 64         // rows per block in main kernel
#define CK 64         // codebook chunk
#define LDP 260       // padded LDS row stride (floats)
#define FIXSCALE 16777216.0f   // 2^24 fixed-point for deterministic atomics

// ws layout (~7.4 KB):
//   u64 acc_s[256] @ 0, u64 acc_q[256] @ 2048,
//   f32 meanb[256] @ 4096, f32 rsb[256] @ 5120, f32 cnorm[320] @ 6144

// ---------------- kernel 0: zero the fixed-point accumulators ---------------
__global__ __launch_bounds__(256) void k_zero(unsigned long long* __restrict__ acc) {
  acc[threadIdx.x] = 0ull;
  acc[256 + threadIdx.x] = 0ull;
}

// ---------------- kernel 1: per-block channel partials -> fixed-point atomics
__global__ __launch_bounds__(256) void k_stats_partial(const float* __restrict__ x,
                                                       unsigned long long* __restrict__ acc) {
  const int d = threadIdx.x;          // channel
  const int blk = blockIdx.x;         // 512 blocks, 256 rows each
  const float* p = x + (size_t)blk * 256 * D + d;
  float s = 0.f, q = 0.f;
  #pragma unroll 4
  for (int r = 0; r < 256; ++r) {
    float v = p[(size_t)r * D];
    s += v;
    q = fmaf(v, v, q);
  }
  long long si = llrintf(s * FIXSCALE);
  long long qi = llrintf(q * FIXSCALE);
  atomicAdd(&acc[d],       (unsigned long long)si);
  atomicAdd(&acc[256 + d], (unsigned long long)qi);
}

// ---------------- kernel 2: finalize stats + codebook norms -----------------
__global__ __launch_bounds__(256) void k_stats_final(const unsigned long long* __restrict__ acc,
                                                     const float* __restrict__ cb,
                                                     float* __restrict__ meanb,
                                                     float* __restrict__ rsb,
                                                     float* __restrict__ cnorm) {
  const int t = threadIdx.x;
  if (blockIdx.x == 0) {
    double s = (double)(long long)acc[t]       / (double)FIXSCALE;
    double q = (double)(long long)acc[256 + t] / (double)FIXSCALE;
    double mean = s / (double)NROW;
    double var  = q / (double)NROW - mean * mean;   // biased, matches torch/jnp
    meanb[t] = (float)mean;
    rsb[t]   = (float)(1.0 / sqrt(var + (double)BN_EPS));
  } else {
    for (int code = t; code < K; code += 256) {
      const float* c = cb + (size_t)code * D;
      float s = 0.f;
      for (int dd = 0; dd < D; ++dd) s = fmaf(c[dd], c[dd], s);
      cnorm[code] = s;
    }
  }
}

// ---------------- kernel 3: normalize + nearest-code + gather ---------------
__global__ __launch_bounds__(256) void k_main(const float* __restrict__ x,
                                              const float* __restrict__ w,
                                              const float* __restrict__ bias,
                                              const float* __restrict__ cb,
                                              const float* __restrict__ meanb,
                                              const float* __restrict__ rsb,
                                              const float* __restrict__ cnorm,
                                              float* __restrict__ out) {
  __shared__ float xbl[RT * LDP];     // 66,560 B
  __shared__ float cbl[CK * LDP];     // 66,560 B
  __shared__ float sxp[RT * 4];
  __shared__ float sx[RT];
  __shared__ float cnl[CK];
  __shared__ float redv[16 * RT];
  __shared__ int   redi[16 * RT];
  __shared__ int   bi[RT];

  const int t = threadIdx.x;
  const int row0 = (int)blockIdx.x * RT;

  // ---- stage normalized xb tile + per-row sum-of-squares partials ----
  {
    const int lr = t >> 2;            // local row 0..63
    const int part = t & 3;           // quarter of the 256 dims
    const int d0 = part * 64;
    const float* xp = x + (size_t)(row0 + lr) * D + d0;
    float acc = 0.f;
    #pragma unroll
    for (int e = 0; e < 16; ++e) {
      float4 xv = *(const float4*)(xp + e * 4);
      float4 mv = *(const float4*)(meanb + d0 + e * 4);
      float4 rv = *(const float4*)(rsb + d0 + e * 4);
      float4 wv = *(const float4*)(w + d0 + e * 4);
      float4 bv = *(const float4*)(bias + d0 + e * 4);
      float4 o;
      o.x = ((xv.x - mv.x) * rv.x) * wv.x + bv.x;
      o.y = ((xv.y - mv.y) * rv.y) * wv.y + bv.y;
      o.z = ((xv.z - mv.z) * rv.z) * wv.z + bv.z;
      o.w = ((xv.w - mv.w) * rv.w) * wv.w + bv.w;
      acc = fmaf(o.x, o.x, acc);
      acc = fmaf(o.y, o.y, acc);
      acc = fmaf(o.z, o.z, acc);
      acc = fmaf(o.w, o.w, acc);
      *(float4*)&xbl[lr * LDP + d0 + e * 4] = o;
    }
    sxp[lr * 4 + part] = acc;
  }
  __syncthreads();
  if (t < RT) {
    sx[t] = ((sxp[t * 4 + 0] + sxp[t * 4 + 1]) + sxp[t * 4 + 2]) + sxp[t * 4 + 3];
  }

  const int rg = t & 15;              // row group
  const int cg = t >> 4;              // code group 0..15
  float bval[4];
  int   bidx[4];
  #pragma unroll
  for (int i = 0; i < 4; ++i) { bval[i] = 3.4e38f; bidx[i] = 0; }

  for (int ch = 0; ch < 5; ++ch) {
    __syncthreads();                  // prev-chunk readers done; sx visible on ch==0
    // ---- stage codebook chunk ----
    {
      const int lc = t >> 2;
      const int part = t & 3;
      const int d0 = part * 64;
      const float* cp = cb + (size_t)(ch * CK + lc) * D + d0;
      #pragma unroll
      for (int e = 0; e < 16; ++e) {
        *(float4*)&cbl[lc * LDP + d0 + e * 4] = *(const float4*)(cp + e * 4);
      }
      if (t < CK) cnl[t] = cnorm[ch * CK + t];
    }
    __syncthreads();

    float acc[4][4];
    #pragma unroll
    for (int i = 0; i < 4; ++i)
      #pragma unroll
      for (int j = 0; j < 4; ++j) acc[i][j] = 0.f;

    #pragma unroll 2
    for (int kq = 0; kq < 64; ++kq) {
      float4 xv[4], cv[4];
      #pragma unroll
      for (int i = 0; i < 4; ++i)
        xv[i] = *(const float4*)&xbl[(i * 16 + rg) * LDP + kq * 4];
      #pragma unroll
      for (int j = 0; j < 4; ++j)
        cv[j] = *(const float4*)&cbl[(j * 16 + cg) * LDP + kq * 4];
      #pragma unroll
      for (int i = 0; i < 4; ++i)
        #pragma unroll
        for (int j = 0; j < 4; ++j) {
          acc[i][j] = fmaf(xv[i].x, cv[j].x, acc[i][j]);
          acc[i][j] = fmaf(xv[i].y, cv[j].y, acc[i][j]);
          acc[i][j] = fmaf(xv[i].z, cv[j].z, acc[i][j]);
          acc[i][j] = fmaf(xv[i].w, cv[j].w, acc[i][j]);
        }
    }

    // ---- distances + running lexicographic argmin ----
    #pragma unroll
    for (int i = 0; i < 4; ++i) {
      const float sxr = sx[i * 16 + rg];
      #pragma unroll
      for (int j = 0; j < 4; ++j) {
        const int code = ch * CK + j * 16 + cg;
        const float d2 = (sxr - 2.0f * acc[i][j]) + cnl[j * 16 + cg];
        if (d2 < bval[i] || (d2 == bval[i] && code < bidx[i])) {
          bval[i] = d2; bidx[i] = code;
        }
      }
    }
  }

  // ---- cross-thread argmin per row ----
  __syncthreads();
  #pragma unroll
  for (int i = 0; i < 4; ++i) {
    redv[cg * RT + i * 16 + rg] = bval[i];
    redi[cg * RT + i * 16 + rg] = bidx[i];
  }
  __syncthreads();
  if (t < RT) {
    float bv = redv[t];
    int   bx = redi[t];
    for (int c = 1; c < 16; ++c) {
      float v = redv[c * RT + t];
      int  ix = redi[c * RT + t];
      if (v < bv || (v == bv && ix < bx)) { bv = v; bx = ix; }
    }
    bi[t] = bx;
    out[(size_t)NROW * D + row0 + t] = (float)bx;   // indices region, f32
  }
  __syncthreads();

  // ---- gather chosen codes (exact f32 copy), coalesced 64B per 4 lanes ----
  {
    const int lr = t >> 2;            // local row
    const int q = t & 3;              // quad within 16-float chunk
    const int code = bi[lr];
    const float* cp = cb + (size_t)code * D;
    float* op = out + (size_t)(row0 + lr) * D;
    #pragma unroll
    for (int e = 0; e < 16; ++e) {
      *(float4*)(op + e * 16 + q * 4) = *(const float4*)(cp + e * 16 + q * 4);
    }
  }
}

extern "C" void kernel_launch(void* const* d_in, const int* in_sizes, int n_in,
                              void* d_out, int out_size, void* d_ws, size_t ws_size,
                              hipStream_t stream) {
  const float* x    = (const float*)d_in[0];
  const float* w    = (const float*)d_in[1];
  const float* bias = (const float*)d_in[2];
  const float* cb   = (const float*)d_in[3];
  float* out = (float*)d_out;

  unsigned long long* acc = (unsigned long long*)d_ws;      // 512 u64 = 4 KB
  float* fbase = (float*)((char*)d_ws + 4096);
  float* meanb = fbase;            // 256
  float* rsb   = fbase + 256;      // 256
  float* cnorm = fbase + 512;      // 320

  k_zero<<<1, 256, 0, stream>>>(acc);
  k_stats_partial<<<512, 256, 0, stream>>>(x, acc);
  k_stats_final<<<2, 256, 0, stream>>>(acc, cb, meanb, rsb, cnorm);
  k_main<<<NROW / RT, 256, 0, stream>>>(x, w, bias, cb, meanb, rsb, cnorm, out);
}

// Round 4
// 220.595 us; speedup vs baseline: 2.6758x; 2.6758x over previous
//
#include <hip/hip_runtime.h>
#include <hip/hip_bf16.h>

#define NROW 131072   // B*L
#define D 256
#define K 320
#define BN_EPS 1e-5f
#define RT 64         // rows per block in main kernel
#define FIXSCALE 16777216.0f   // 2^24 fixed-point for deterministic atomics

typedef _Float16 half8 __attribute__((ext_vector_type(8)));
typedef float f32x4 __attribute__((ext_vector_type(4)));

// ws layout:
//   u64 acc[512]        @ 0       (4 KB)
//   f32 meanb[256]      @ 4096
//   f32 rsb[256]        @ 5120
//   f32 cnorm[320]      @ 6144    (ends 7424)
//   f16 cbh[20*8*64*8]  @ 8192    (160 KB)  codebook hi, MFMA-fragment order
//   f16 cbl[...]        @ 172032  (160 KB)  codebook lo

// ---------------- kernel 0: zero the fixed-point accumulators ---------------
__global__ __launch_bounds__(256) void k_zero(unsigned long long* __restrict__ acc) {
  acc[threadIdx.x] = 0ull;
  acc[256 + threadIdx.x] = 0ull;
}

// ---------------- kernel 1: per-block channel partials -> fixed-point atomics
__global__ __launch_bounds__(256) void k_stats_partial(const float* __restrict__ x,
                                                       unsigned long long* __restrict__ acc) {
  const int d = threadIdx.x;
  const int blk = blockIdx.x;         // 512 blocks, 256 rows each
  const float* p = x + (size_t)blk * 256 * D + d;
  float s = 0.f, q = 0.f;
  #pragma unroll 4
  for (int r = 0; r < 256; ++r) {
    float v = p[(size_t)r * D];
    s += v;
    q = fmaf(v, v, q);
  }
  long long si = llrintf(s * FIXSCALE);
  long long qi = llrintf(q * FIXSCALE);
  atomicAdd(&acc[d],       (unsigned long long)si);
  atomicAdd(&acc[256 + d], (unsigned long long)qi);
}

// ---------------- kernel 2: finalize stats + codebook norms -----------------
__global__ __launch_bounds__(256) void k_stats_final(const unsigned long long* __restrict__ acc,
                                                     const float* __restrict__ cb,
                                                     float* __restrict__ meanb,
                                                     float* __restrict__ rsb,
                                                     float* __restrict__ cnorm) {
  const int t = threadIdx.x;
  if (blockIdx.x == 0) {
    double s = (double)(long long)acc[t]       / (double)FIXSCALE;
    double q = (double)(long long)acc[256 + t] / (double)FIXSCALE;
    double mean = s / (double)NROW;
    double var  = q / (double)NROW - mean * mean;
    meanb[t] = (float)mean;
    rsb[t]   = (float)(1.0 / sqrt(var + (double)BN_EPS));
  } else {
    for (int code = t; code < K; code += 256) {
      const float* c = cb + (size_t)code * D;
      float s = 0.f;
      for (int dd = 0; dd < D; ++dd) s = fmaf(c[dd], c[dd], s);
      cnorm[code] = s;
    }
  }
}

// ---------------- kernel 2b: split codebook to fp16 hi/lo, fragment order ---
// Fragment layout for mfma_f32_16x16x32_f16 B-operand (B^T row-major pattern):
// lane l holds code = n0 + (l&15), k-elems d = ks*32 + (l>>4)*8 .. +8.
// Stored so the main-kernel load  cbh[(( (nt*8+ks)*64 + lane )*8] is coalesced.
__global__ __launch_bounds__(64) void k_cbprep(const float* __restrict__ cb,
                                               _Float16* __restrict__ cbh,
                                               _Float16* __restrict__ cbl) {
  const int nt = blockIdx.x;   // 0..19  (16-code tile)
  const int ks = blockIdx.y;   // 0..7   (32-k step)
  const int l  = threadIdx.x;  // 0..63
  const int code = nt * 16 + (l & 15);
  const int d0 = ks * 32 + (l >> 4) * 8;
  const float* src = cb + (size_t)code * D + d0;
  const size_t base = ((size_t)(nt * 8 + ks) * 64 + l) * 8;
  #pragma unroll
  for (int j = 0; j < 8; ++j) {
    float v = src[j];
    _Float16 h = (_Float16)v;
    _Float16 lo = (_Float16)(v - (float)h);
    cbh[base + j] = h;
    cbl[base + j] = lo;
  }
}

// ---------------- kernel 3: normalize + MFMA distances + argmin + gather ----
__global__ __launch_bounds__(256, 2) void k_main(const float* __restrict__ x,
                                                 const float* __restrict__ w,
                                                 const float* __restrict__ bias,
                                                 const float* __restrict__ cb,
                                                 const float* __restrict__ meanb,
                                                 const float* __restrict__ rsb,
                                                 const float* __restrict__ cnorm,
                                                 const _Float16* __restrict__ cbh,
                                                 const _Float16* __restrict__ cbl,
                                                 float* __restrict__ out) {
  __shared__ _Float16 xh[RT * 256];   // 32 KB, XOR-swizzled 16B chunks
  __shared__ _Float16 xl[RT * 256];   // 32 KB
  __shared__ float sxp[RT * 4];
  __shared__ float sx[RT];
  __shared__ float redv[4 * RT];
  __shared__ int   redi[4 * RT];
  __shared__ int   bsel[RT];

  const int t = threadIdx.x;
  const int row0 = (int)blockIdx.x * RT;
  const int lane = t & 63;
  const int wv = t >> 6;              // wave 0..3: codes [wv*80, wv*80+80)
  const int c15 = lane & 15;
  const int g = lane >> 4;

  // ---- stage normalized xb tile as fp16 hi/lo + per-row sum-sq partials ----
  {
    const int lr = t >> 2;            // local row 0..63
    const int qt = t & 3;             // dim quarter
    const int d0 = qt * 64;
    const float* xp = x + (size_t)(row0 + lr) * D + d0;
    float accq = 0.f;
    half8 hb, lb;
    char* xhb = (char*)xh + lr * 512;
    char* xlb = (char*)xl + lr * 512;
    #pragma unroll
    for (int e = 0; e < 16; ++e) {
      float4 xv = *(const float4*)(xp + e * 4);
      float4 mv = *(const float4*)(meanb + d0 + e * 4);
      float4 rv = *(const float4*)(rsb + d0 + e * 4);
      float4 wv4 = *(const float4*)(w + d0 + e * 4);
      float4 bv4 = *(const float4*)(bias + d0 + e * 4);
      float4 o;
      o.x = ((xv.x - mv.x) * rv.x) * wv4.x + bv4.x;
      o.y = ((xv.y - mv.y) * rv.y) * wv4.y + bv4.y;
      o.z = ((xv.z - mv.z) * rv.z) * wv4.z + bv4.z;
      o.w = ((xv.w - mv.w) * rv.w) * wv4.w + bv4.w;
      accq = fmaf(o.x, o.x, accq);
      accq = fmaf(o.y, o.y, accq);
      accq = fmaf(o.z, o.z, accq);
      accq = fmaf(o.w, o.w, accq);
      const int sl = (e & 1) * 4;
      hb[sl + 0] = (_Float16)o.x;  lb[sl + 0] = (_Float16)(o.x - (float)hb[sl + 0]);
      hb[sl + 1] = (_Float16)o.y;  lb[sl + 1] = (_Float16)(o.y - (float)hb[sl + 1]);
      hb[sl + 2] = (_Float16)o.z;  lb[sl + 2] = (_Float16)(o.z - (float)hb[sl + 2]);
      hb[sl + 3] = (_Float16)o.w;  lb[sl + 3] = (_Float16)(o.w - (float)hb[sl + 3]);
      if (e & 1) {
        const int c = qt * 8 + (e >> 1);        // 16B chunk index 0..31
        const int sc = c ^ (lr & 7);            // XOR swizzle
        *(half8*)(xhb + sc * 16) = hb;
        *(half8*)(xlb + sc * 16) = lb;
      }
    }
    sxp[lr * 4 + qt] = accq;
  }
  __syncthreads();
  if (t < RT) {
    sx[t] = ((sxp[t * 4 + 0] + sxp[t * 4 + 1]) + sxp[t * 4 + 2]) + sxp[t * 4 + 3];
  }
  __syncthreads();

  // ---- per-lane constants ----
  float cnreg[5];
  #pragma unroll
  for (int tt = 0; tt < 5; ++tt) cnreg[tt] = cnorm[wv * 80 + tt * 16 + c15];
  float sxr[4][4];
  #pragma unroll
  for (int i = 0; i < 4; ++i)
    #pragma unroll
    for (int r = 0; r < 4; ++r) sxr[i][r] = sx[i * 16 + g * 4 + r];

  // ---- MFMA k-loop: acc[i][tt] over 4 row-tiles x 5 code-tiles ----
  f32x4 acc[4][5];
  #pragma unroll
  for (int i = 0; i < 4; ++i)
    #pragma unroll
    for (int tt = 0; tt < 5; ++tt) acc[i][tt] = (f32x4){0.f, 0.f, 0.f, 0.f};

  #pragma unroll
  for (int ks = 0; ks < 8; ++ks) {
    half8 ah[4], al[4];
    #pragma unroll
    for (int i = 0; i < 4; ++i) {
      const int row = i * 16 + c15;
      const int sc = (ks * 4 + g) ^ (row & 7);
      ah[i] = *(const half8*)((const char*)xh + row * 512 + sc * 16);
      al[i] = *(const half8*)((const char*)xl + row * 512 + sc * 16);
    }
    #pragma unroll
    for (int tt = 0; tt < 5; ++tt) {
      const size_t boff = (((size_t)(wv * 5 + tt) * 8 + ks) * 64 + lane) * 8;
      half8 bh = *(const half8*)(cbh + boff);
      half8 bl = *(const half8*)(cbl + boff);
      #pragma unroll
      for (int i = 0; i < 4; ++i) {
        acc[i][tt] = __builtin_amdgcn_mfma_f32_16x16x32_f16(ah[i], bh, acc[i][tt], 0, 0, 0);
        acc[i][tt] = __builtin_amdgcn_mfma_f32_16x16x32_f16(ah[i], bl, acc[i][tt], 0, 0, 0);
        acc[i][tt] = __builtin_amdgcn_mfma_f32_16x16x32_f16(al[i], bh, acc[i][tt], 0, 0, 0);
      }
    }
  }

  // ---- d2 + running lexicographic argmin (C/D: col=lane&15, row=(lane>>4)*4+r)
  float bv[4][4];
  int   bix[4][4];
  #pragma unroll
  for (int i = 0; i < 4; ++i)
    #pragma unroll
    for (int r = 0; r < 4; ++r) { bv[i][r] = 3.4e38f; bix[i][r] = 0x7fffffff; }

  #pragma unroll
  for (int i = 0; i < 4; ++i)
    #pragma unroll
    for (int tt = 0; tt < 5; ++tt) {
      const int code = wv * 80 + tt * 16 + c15;
      #pragma unroll
      for (int r = 0; r < 4; ++r) {
        const float d2 = (sxr[i][r] - 2.0f * acc[i][tt][r]) + cnreg[tt];
        if (d2 < bv[i][r] || (d2 == bv[i][r] && code < bix[i][r])) {
          bv[i][r] = d2; bix[i][r] = code;
        }
      }
    }

  // butterfly reduce across the 16 lanes holding the same rows
  #pragma unroll
  for (int off = 8; off >= 1; off >>= 1) {
    #pragma unroll
    for (int i = 0; i < 4; ++i)
      #pragma unroll
      for (int r = 0; r < 4; ++r) {
        const float ov = __shfl_xor(bv[i][r], off);
        const int   oi = __shfl_xor(bix[i][r], off);
        if (ov < bv[i][r] || (ov == bv[i][r] && oi < bix[i][r])) {
          bv[i][r] = ov; bix[i][r] = oi;
        }
      }
  }
  if (c15 == 0) {
    #pragma unroll
    for (int i = 0; i < 4; ++i)
      #pragma unroll
      for (int r = 0; r < 4; ++r) {
        const int row = i * 16 + g * 4 + r;
        redv[wv * RT + row] = bv[i][r];
        redi[wv * RT + row] = bix[i][r];
      }
  }
  __syncthreads();

  // combine 4 waves (disjoint ascending code ranges -> strict < keeps lowest)
  if (t < RT) {
    float fv = redv[t];
    int   fi = redi[t];
    #pragma unroll
    for (int w2 = 1; w2 < 4; ++w2) {
      const float v2 = redv[w2 * RT + t];
      const int   i2 = redi[w2 * RT + t];
      if (v2 < fv) { fv = v2; fi = i2; }
    }
    bsel[t] = fi;
    out[(size_t)NROW * D + row0 + t] = (float)fi;
  }
  __syncthreads();

  // ---- gather chosen codes (exact f32 copy) ----
  {
    const int lr = t >> 2;
    const int q = t & 3;
    const int code = bsel[lr];
    const float* cp = cb + (size_t)code * D;
    float* op = out + (size_t)(row0 + lr) * D;
    #pragma unroll
    for (int e = 0; e < 16; ++e) {
      *(float4*)(op + e * 16 + q * 4) = *(const float4*)(cp + e * 16 + q * 4);
    }
  }
}

extern "C" void kernel_launch(void* const* d_in, const int* in_sizes, int n_in,
                              void* d_out, int out_size, void* d_ws, size_t ws_size,
                              hipStream_t stream) {
  const float* x    = (const float*)d_in[0];
  const float* w    = (const float*)d_in[1];
  const float* bias = (const float*)d_in[2];
  const float* cb   = (const float*)d_in[3];
  float* out = (float*)d_out;

  unsigned long long* acc = (unsigned long long*)d_ws;
  float* meanb = (float*)((char*)d_ws + 4096);
  float* rsb   = meanb + 256;
  float* cnorm = rsb + 256;
  _Float16* cbh = (_Float16*)((char*)d_ws + 8192);
  _Float16* cbl = (_Float16*)((char*)d_ws + 8192 + 163840);

  k_zero<<<1, 256, 0, stream>>>(acc);
  k_cbprep<<<dim3(20, 8), 64, 0, stream>>>(cb, cbh, cbl);
  k_stats_partial<<<512, 256, 0, stream>>>(x, acc);
  k_stats_final<<<2, 256, 0, stream>>>(acc, cb, meanb, rsb, cnorm);
  k_main<<<NROW / RT, 256, 0, stream>>>(x, w, bias, cb, meanb, rsb, cnorm, cbh, cbl, out);
}

// Round 5
// 203.196 us; speedup vs baseline: 2.9049x; 1.0856x over previous
//
#include <hip/hip_runtime.h>
#include <hip/hip_bf16.h>

#define NROW 131072   // B*L
#define D 256
#define K 320
#define BN_EPS 1e-5f
#define FIXSCALE 16777216.0f   // 2^24 fixed-point for deterministic atomics
#define XSH 264       // halfs per LDS row: 256 + 8 pad (528 B, 16B-aligned, bank-shift 4)

typedef _Float16 half8 __attribute__((ext_vector_type(8)));
typedef float f32x4 __attribute__((ext_vector_type(4)));

// ws layout:
//   u64 acc[512]        @ 0       (4 KB)
//   f32 meanb[256]      @ 4096
//   f32 rsb[256]        @ 5120
//   f32 cnorm[320]      @ 6144
//   f16 cbh[20*8*64*8]  @ 8192    (160 KB)  codebook hi, MFMA B-fragment order
//   f16 cbl[...]        @ 172032  (160 KB)  codebook lo

// ---------------- kernel 0: zero the fixed-point accumulators ---------------
__global__ __launch_bounds__(256) void k_zero(unsigned long long* __restrict__ acc) {
  acc[threadIdx.x] = 0ull;
  acc[256 + threadIdx.x] = 0ull;
}

// ---------------- kernel 1: per-block channel partials -> fixed-point atomics
__global__ __launch_bounds__(256) void k_stats_partial(const float* __restrict__ x,
                                                       unsigned long long* __restrict__ acc) {
  const int d = threadIdx.x;
  const int blk = blockIdx.x;         // 512 blocks, 256 rows each
  const float* p = x + (size_t)blk * 256 * D + d;
  float s = 0.f, q = 0.f;
  #pragma unroll 4
  for (int r = 0; r < 256; ++r) {
    float v = p[(size_t)r * D];
    s += v;
    q = fmaf(v, v, q);
  }
  long long si = llrintf(s * FIXSCALE);
  long long qi = llrintf(q * FIXSCALE);
  atomicAdd(&acc[d],       (unsigned long long)si);
  atomicAdd(&acc[256 + d], (unsigned long long)qi);
}

// ---------------- kernel 2: finalize stats + codebook norms -----------------
__global__ __launch_bounds__(256) void k_stats_final(const unsigned long long* __restrict__ acc,
                                                     const float* __restrict__ cb,
                                                     float* __restrict__ meanb,
                                                     float* __restrict__ rsb,
                                                     float* __restrict__ cnorm) {
  const int t = threadIdx.x;
  if (blockIdx.x == 0) {
    double s = (double)(long long)acc[t]       / (double)FIXSCALE;
    double q = (double)(long long)acc[256 + t] / (double)FIXSCALE;
    double mean = s / (double)NROW;
    double var  = q / (double)NROW - mean * mean;
    meanb[t] = (float)mean;
    rsb[t]   = (float)(1.0 / sqrt(var + (double)BN_EPS));
  } else {
    for (int code = t; code < K; code += 256) {
      const float* c = cb + (size_t)code * D;
      float s = 0.f;
      for (int dd = 0; dd < D; ++dd) s = fmaf(c[dd], c[dd], s);
      cnorm[code] = s;
    }
  }
}

// ---------------- kernel 2b: split codebook to fp16 hi/lo, fragment order ---
// lane l holds code = nt*16 + (l&15), k-elems d = ks*32 + (l>>4)*8 .. +8
__global__ __launch_bounds__(64) void k_cbprep(const float* __restrict__ cb,
                                               _Float16* __restrict__ cbh,
                                               _Float16* __restrict__ cbl) {
  const int nt = blockIdx.x;   // 0..19
  const int ks = blockIdx.y;   // 0..7
  const int l  = threadIdx.x;  // 0..63
  const int code = nt * 16 + (l & 15);
  const int d0 = ks * 32 + (l >> 4) * 8;
  const float* src = cb + (size_t)code * D + d0;
  const size_t base = ((size_t)(nt * 8 + ks) * 64 + l) * 8;
  #pragma unroll
  for (int j = 0; j < 8; ++j) {
    float v = src[j];
    _Float16 h = (_Float16)v;
    _Float16 lo = (_Float16)(v - (float)h);
    cbh[base + j] = h;
    cbl[base + j] = lo;
  }
}

// ---------------- kernel 3: normalize + MFMA distances + argmin + gather ----
__global__ __launch_bounds__(512, 4) void k_main(const float* __restrict__ x,
                                                 const float* __restrict__ w,
                                                 const float* __restrict__ bias,
                                                 const float* __restrict__ cb,
                                                 const float* __restrict__ meanb,
                                                 const float* __restrict__ rsb,
                                                 const float* __restrict__ cnorm,
                                                 const _Float16* __restrict__ cbh,
                                                 const _Float16* __restrict__ cbl,
                                                 float* __restrict__ out) {
  __shared__ _Float16 xh[64 * XSH];   // 33,792 B (padded rows -> conflict-free b128)
  __shared__ _Float16 xl[64 * XSH];   // 33,792 B
  __shared__ float sxp[64 * 8];
  __shared__ float sx[64];
  __shared__ float redv[4 * 64];
  __shared__ int   redi[4 * 64];
  __shared__ int   bsel[64];

  const int t = threadIdx.x;
  const int row0 = (int)blockIdx.x * 64;
  const int lane = t & 63;
  const int wv = t >> 6;              // wave 0..7
  const int cgrp = wv & 3;            // code group: codes [cgrp*80, +80)
  const int rhalf = wv >> 2;          // row half: 0 -> rows 0-31, 1 -> rows 32-63
  const int c15 = lane & 15;
  const int g = lane >> 4;

  // ---- stage normalized xb tile as fp16 hi/lo + per-row sum-sq partials ----
  {
    const int lr = t >> 3;            // local row 0..63
    const int oct = t & 7;            // 32-dim slice
    const int d0 = oct * 32;
    const float* xp = x + (size_t)(row0 + lr) * D + d0;
    float accq = 0.f;
    half8 hb, lb;
    _Float16* xhb = xh + lr * XSH;
    _Float16* xlb = xl + lr * XSH;
    #pragma unroll
    for (int e = 0; e < 8; ++e) {
      float4 xv = *(const float4*)(xp + e * 4);
      float4 mv = *(const float4*)(meanb + d0 + e * 4);
      float4 rv = *(const float4*)(rsb + d0 + e * 4);
      float4 wv4 = *(const float4*)(w + d0 + e * 4);
      float4 bv4 = *(const float4*)(bias + d0 + e * 4);
      float4 o;
      o.x = ((xv.x - mv.x) * rv.x) * wv4.x + bv4.x;
      o.y = ((xv.y - mv.y) * rv.y) * wv4.y + bv4.y;
      o.z = ((xv.z - mv.z) * rv.z) * wv4.z + bv4.z;
      o.w = ((xv.w - mv.w) * rv.w) * wv4.w + bv4.w;
      accq = fmaf(o.x, o.x, accq);
      accq = fmaf(o.y, o.y, accq);
      accq = fmaf(o.z, o.z, accq);
      accq = fmaf(o.w, o.w, accq);
      const int sl = (e & 1) * 4;
      hb[sl + 0] = (_Float16)o.x;  lb[sl + 0] = (_Float16)(o.x - (float)hb[sl + 0]);
      hb[sl + 1] = (_Float16)o.y;  lb[sl + 1] = (_Float16)(o.y - (float)hb[sl + 1]);
      hb[sl + 2] = (_Float16)o.z;  lb[sl + 2] = (_Float16)(o.z - (float)hb[sl + 2]);
      hb[sl + 3] = (_Float16)o.w;  lb[sl + 3] = (_Float16)(o.w - (float)hb[sl + 3]);
      if (e & 1) {
        const int c = oct * 4 + (e >> 1);       // 16B chunk index 0..31
        *(half8*)(xhb + c * 8) = hb;
        *(half8*)(xlb + c * 8) = lb;
      }
    }
    sxp[lr * 8 + oct] = accq;
  }
  __syncthreads();
  if (t < 64) {
    float s = 0.f;
    #pragma unroll
    for (int j = 0; j < 8; ++j) s += sxp[t * 8 + j];
    sx[t] = s;
  }
  __syncthreads();

  // ---- per-lane constants ----
  float cnreg[5];
  #pragma unroll
  for (int tt = 0; tt < 5; ++tt) cnreg[tt] = cnorm[cgrp * 80 + tt * 16 + c15];
  float sxr[2][4];
  #pragma unroll
  for (int i = 0; i < 2; ++i)
    #pragma unroll
    for (int r = 0; r < 4; ++r) sxr[i][r] = sx[(rhalf * 2 + i) * 16 + g * 4 + r];

  // ---- MFMA k-loop: acc[i][tt] over 2 row-tiles x 5 code-tiles ----
  f32x4 acc[2][5];
  #pragma unroll
  for (int i = 0; i < 2; ++i)
    #pragma unroll
    for (int tt = 0; tt < 5; ++tt) acc[i][tt] = (f32x4){0.f, 0.f, 0.f, 0.f};

  #pragma unroll
  for (int ks = 0; ks < 8; ++ks) {
    half8 ah[2], al[2];
    #pragma unroll
    for (int i = 0; i < 2; ++i) {
      const int row = (rhalf * 2 + i) * 16 + c15;
      ah[i] = *(const half8*)(xh + row * XSH + (ks * 4 + g) * 8);
      al[i] = *(const half8*)(xl + row * XSH + (ks * 4 + g) * 8);
    }
    #pragma unroll
    for (int tt = 0; tt < 5; ++tt) {
      const size_t boff = (((size_t)(cgrp * 5 + tt) * 8 + ks) * 64 + lane) * 8;
      half8 bh = *(const half8*)(cbh + boff);
      half8 bl = *(const half8*)(cbl + boff);
      #pragma unroll
      for (int i = 0; i < 2; ++i) {
        acc[i][tt] = __builtin_amdgcn_mfma_f32_16x16x32_f16(ah[i], bh, acc[i][tt], 0, 0, 0);
        acc[i][tt] = __builtin_amdgcn_mfma_f32_16x16x32_f16(ah[i], bl, acc[i][tt], 0, 0, 0);
        acc[i][tt] = __builtin_amdgcn_mfma_f32_16x16x32_f16(al[i], bh, acc[i][tt], 0, 0, 0);
      }
    }
  }

  // ---- d2 + running lexicographic argmin (C/D: col=lane&15, row=(lane>>4)*4+r)
  float bv[2][4];
  int   bix[2][4];
  #pragma unroll
  for (int i = 0; i < 2; ++i)
    #pragma unroll
    for (int r = 0; r < 4; ++r) { bv[i][r] = 3.4e38f; bix[i][r] = 0x7fffffff; }

  #pragma unroll
  for (int i = 0; i < 2; ++i)
    #pragma unroll
    for (int tt = 0; tt < 5; ++tt) {
      const int code = cgrp * 80 + tt * 16 + c15;
      #pragma unroll
      for (int r = 0; r < 4; ++r) {
        const float d2 = (sxr[i][r] - 2.0f * acc[i][tt][r]) + cnreg[tt];
        if (d2 < bv[i][r] || (d2 == bv[i][r] && code < bix[i][r])) {
          bv[i][r] = d2; bix[i][r] = code;
        }
      }
    }

  // butterfly reduce across the 16 lanes holding the same rows
  #pragma unroll
  for (int off = 8; off >= 1; off >>= 1) {
    #pragma unroll
    for (int i = 0; i < 2; ++i)
      #pragma unroll
      for (int r = 0; r < 4; ++r) {
        const float ov = __shfl_xor(bv[i][r], off);
        const int   oi = __shfl_xor(bix[i][r], off);
        if (ov < bv[i][r] || (ov == bv[i][r] && oi < bix[i][r])) {
          bv[i][r] = ov; bix[i][r] = oi;
        }
      }
  }
  if (c15 == 0) {
    #pragma unroll
    for (int i = 0; i < 2; ++i)
      #pragma unroll
      for (int r = 0; r < 4; ++r) {
        const int row = (rhalf * 2 + i) * 16 + g * 4 + r;
        redv[cgrp * 64 + row] = bv[i][r];
        redi[cgrp * 64 + row] = bix[i][r];
      }
  }
  __syncthreads();

  // combine 4 code-groups (disjoint ascending ranges -> strict < keeps lowest)
  if (t < 64) {
    float fv = redv[t];
    int   fi = redi[t];
    #pragma unroll
    for (int w2 = 1; w2 < 4; ++w2) {
      const float v2 = redv[w2 * 64 + t];
      const int   i2 = redi[w2 * 64 + t];
      if (v2 < fv) { fv = v2; fi = i2; }
    }
    bsel[t] = fi;
    out[(size_t)NROW * D + row0 + t] = (float)fi;
  }
  __syncthreads();

  // ---- gather chosen codes (exact f32 copy), 128B segments per 8 lanes ----
  {
    const int lr = t >> 3;
    const int f4i = t & 7;
    const int code = bsel[lr];
    const float* cp = cb + (size_t)code * D;
    float* op = out + (size_t)(row0 + lr) * D;
    #pragma unroll
    for (int e = 0; e < 8; ++e) {
      *(float4*)(op + (f4i + 8 * e) * 4) = *(const float4*)(cp + (f4i + 8 * e) * 4);
    }
  }
}

extern "C" void kernel_launch(void* const* d_in, const int* in_sizes, int n_in,
                              void* d_out, int out_size, void* d_ws, size_t ws_size,
                              hipStream_t stream) {
  const float* x    = (const float*)d_in[0];
  const float* w    = (const float*)d_in[1];
  const float* bias = (const float*)d_in[2];
  const float* cb   = (const float*)d_in[3];
  float* out = (float*)d_out;

  unsigned long long* acc = (unsigned long long*)d_ws;
  float* meanb = (float*)((char*)d_ws + 4096);
  float* rsb   = meanb + 256;
  float* cnorm = rsb + 256;
  _Float16* cbh = (_Float16*)((char*)d_ws + 8192);
  _Float16* cbl = (_Float16*)((char*)d_ws + 8192 + 163840);

  k_zero<<<1, 256, 0, stream>>>(acc);
  k_cbprep<<<dim3(20, 8), 64, 0, stream>>>(cb, cbh, cbl);
  k_stats_partial<<<512, 256, 0, stream>>>(x, acc);
  k_stats_final<<<2, 256, 0, stream>>>(acc, cb, meanb, rsb, cnorm);
  k_main<<<NROW / 64, 512, 0, stream>>>(x, w, bias, cb, meanb, rsb, cnorm, cbh, cbl, out);
}